// Round 7
// baseline (7876.291 us; speedup 1.0000x reference)
//
#include <hip/hip_runtime.h>
#include <math.h>

#define T_STEPS 512
#define BATCH   256
#define DFEAT   128
#define DIN     257
#define DINP    288   // 257 padded to multiple of 32 (zeros)
#define HID     1024
#define G3      3072
#define OUTD    128

#define WSTR      1032                 // W_hh LDS row stride (shorts): 1024 + 8 pad
#define BUF_OFF   99072                // 48*1032*2 bytes of W_hh slice
#define HT_OFF    (BUF_OFF + 16384)    // + 16 KB reduction buffer
#define LDS_BYTES (HT_OFF + 2048)      // + 2 KB htile = 117504

typedef __bf16 bf16x8 __attribute__((ext_vector_type(8)));
typedef float  f32x4  __attribute__((ext_vector_type(4)));

__device__ __forceinline__ unsigned short f2bf(float f) {
    unsigned int u = __float_as_uint(f);
    u += 0x7FFF + ((u >> 16) & 1);   // round-to-nearest-even
    return (unsigned short)(u >> 16);
}

// Coherent (agent-scope, cache-bypassing) 8B h access: h lives at the device
// coherence point — no per-step fences needed.
__device__ __forceinline__ bf16x8 load_h_frag(const unsigned long long* p) {
    union { unsigned long long u[2]; bf16x8 v; } t;
    t.u[0] = __hip_atomic_load(p,     __ATOMIC_RELAXED, __HIP_MEMORY_SCOPE_AGENT);
    t.u[1] = __hip_atomic_load(p + 1, __ATOMIC_RELAXED, __HIP_MEMORY_SCOPE_AGENT);
    return t.v;
}

// Build xt[t][b][c] (bf16, zero-padded to DINP) from x[b][t][d], mask[b][t][d], ti[b][t]
__global__ void build_xt(const float* __restrict__ x, const float* __restrict__ mask,
                         const float* __restrict__ ti, unsigned short* __restrict__ xt) {
    const int N = T_STEPS * BATCH * DINP;
    for (int idx = blockIdx.x * blockDim.x + threadIdx.x; idx < N;
         idx += gridDim.x * blockDim.x) {
        int c   = idx % DINP;
        int rem = idx / DINP;
        int b   = rem % BATCH;
        int t   = rem / BATCH;
        float v;
        if (c < DFEAT)            v = x[(b * T_STEPS + t) * DFEAT + c];
        else if (c < 2 * DFEAT)   v = mask[(b * T_STEPS + t) * DFEAT + (c - DFEAT)];
        else if (c == 2 * DFEAT)  v = ti[b * T_STEPS + t];
        else                      v = 0.f;
        xt[idx] = f2bf(v);
    }
}

// Persistent GRU: 256 blocks (1/CU), 512 threads = 8 waves.
// Wave = (batch-subtile s = w&3, K-half kh = w>>2). Per wave: 16 h-fragments
// (64 VGPRs) -> full register burst, no compiler splitting. 2-way K reduction
// through a b128 LDS buffer. Sync: one counter per (t,g), tid0 polls.
__global__ __launch_bounds__(512, 1) void gru_persist(
    const unsigned short* __restrict__ xt,
    const float* __restrict__ W_ih, const float* __restrict__ W_hh,
    const float* __restrict__ b_ih, const float* __restrict__ b_hh,
    unsigned long long* hb0, unsigned long long* hb1,
    float* __restrict__ hF, unsigned int* flags)
{
    extern __shared__ char smem[];
    unsigned short* wlds  = (unsigned short*)smem;            // 48 x 1032 shorts
    char*           bufb  = smem + BUF_OFF;                   // 16 KB f32x4 buffer
    unsigned short* htile = (unsigned short*)(smem + HT_OFF); // 64 x 16 shorts

    const int tid = threadIdx.x;
    const int w   = tid >> 6;          // wave 0..7
    const int s   = w & 3;             // batch subtile 0..3
    const int kh  = w >> 2;            // K half 0..1
    const int l   = tid & 63;
    const int ln  = l & 15;            // unit lane / A row lane
    const int q   = l >> 4;            // quad
    const int g   = blockIdx.x >> 6;   // batch group 0..3
    const int ut  = blockIdx.x & 63;   // unit tile 0..63
    const int u0  = ut * 16;
    const int bb  = g * 64;
    const int myb = bb + s * 16;       // this wave's batch base

    // ---- load W_hh slice into LDS (f32 -> bf16), rows = gate*16 + u ----
    for (int i = tid; i < 48 * 512; i += 512) {
        int row = i >> 9;                 // 0..47
        int c2  = (i & 511) * 2;          // 0..1022 step 2
        int grow = (row >> 4) * HID + u0 + (row & 15);
        const float* src = W_hh + (size_t)grow * HID + c2;
        unsigned int lo = f2bf(src[0]), hi = f2bf(src[1]);
        *(unsigned int*)(&wlds[row * WSTR + c2]) = lo | (hi << 16);
    }

    // ---- W_ih fragments in regs: kh=0 -> x-chunks 0..3, kh=1 -> 4..8 ----
    bf16x8 xw[5][3];
    const int nxc = kh ? 5 : 4;
    #pragma unroll
    for (int xi = 0; xi < 5; xi++) {
        if (xi < nxc) {
            int cx = (kh ? 4 : 0) + xi;
            #pragma unroll
            for (int G = 0; G < 3; G++) {
                unsigned short tmp[8];
                #pragma unroll
                for (int j = 0; j < 8; j++) {
                    int col = cx * 32 + q * 8 + j;
                    float f = (col < DIN)
                        ? W_ih[(size_t)(G * HID + u0 + ln) * DIN + col] : 0.f;
                    tmp[j] = f2bf(f);
                }
                xw[xi][G] = *(bf16x8*)tmp;
            }
        }
    }

    // ---- biases (per lane unit), fp32 master h in regs (kh=0 waves own it) ----
    const int gu = u0 + ln;
    const float bR  = b_ih[gu]            + b_hh[gu];
    const float bZ  = b_ih[HID + gu]      + b_hh[HID + gu];
    const float bIN = b_ih[2 * HID + gu];
    const float bHN = b_hh[2 * HID + gu];
    float hreg[4] = {0.f, 0.f, 0.f, 0.f};

    __syncthreads();

    unsigned long long* hbufs[2] = {hb0, hb1};

    for (int t = 0; t < T_STEPS; t++) {
        const unsigned long long* hrd = hbufs[t & 1];
        unsigned long long* hwr = hbufs[(t + 1) & 1];

        // ---- wait for h(t): single aggregated counter, tid0 polls ----
        if (t > 0 && tid == 0) {
            const unsigned int* flg = flags + (size_t)(t - 1) * 4 + g;
            while (__hip_atomic_load(flg, __ATOMIC_RELAXED,
                                     __HIP_MEMORY_SCOPE_AGENT) != 64u)
                __builtin_amdgcn_s_sleep(2);
        }
        __syncthreads();   // [A]

        // ---- issue the full h burst: 16 fragments = 64 VGPRs, all in flight ----
        bf16x8 hfrag[16];
        const unsigned long long* hbase = hrd + (((size_t)(myb + ln) * HID) >> 2);
        #pragma unroll
        for (int ci = 0; ci < 16; ci++) {
            int k0 = (kh * 16 + ci) * 32;
            hfrag[ci] = load_h_frag(hbase + ((k0 + q * 8) >> 2));
        }

        f32x4 aR  = {0.f, 0.f, 0.f, 0.f};
        f32x4 aZ  = {0.f, 0.f, 0.f, 0.f};
        f32x4 aIN = {0.f, 0.f, 0.f, 0.f};
        f32x4 aHN = {0.f, 0.f, 0.f, 0.f};

        // ---- x-part (hides h-load latency) ----
        const unsigned short* xrow = xt + (size_t)t * BATCH * DINP
                                        + (size_t)(myb + ln) * DINP;
        #pragma unroll
        for (int xi = 0; xi < 5; xi++) {
            if (xi < nxc) {
                int cx = (kh ? 4 : 0) + xi;
                bf16x8 a = *(const bf16x8*)(xrow + cx * 32 + q * 8);
                aR  = __builtin_amdgcn_mfma_f32_16x16x32_bf16(a, xw[xi][0], aR,  0, 0, 0);
                aZ  = __builtin_amdgcn_mfma_f32_16x16x32_bf16(a, xw[xi][1], aZ,  0, 0, 0);
                aIN = __builtin_amdgcn_mfma_f32_16x16x32_bf16(a, xw[xi][2], aIN, 0, 0, 0);
            }
        }

        // ---- h-part MFMAs from registers ----
        #pragma unroll
        for (int ci = 0; ci < 16; ci++) {
            int k0 = (kh * 16 + ci) * 32;
            bf16x8 br = *(const bf16x8*)(&wlds[(0  + ln) * WSTR + k0 + q * 8]);
            bf16x8 bz = *(const bf16x8*)(&wlds[(16 + ln) * WSTR + k0 + q * 8]);
            bf16x8 bn = *(const bf16x8*)(&wlds[(32 + ln) * WSTR + k0 + q * 8]);
            aR  = __builtin_amdgcn_mfma_f32_16x16x32_bf16(hfrag[ci], br, aR,  0, 0, 0);
            aZ  = __builtin_amdgcn_mfma_f32_16x16x32_bf16(hfrag[ci], bz, aZ,  0, 0, 0);
            aHN = __builtin_amdgcn_mfma_f32_16x16x32_bf16(hfrag[ci], bn, aHN, 0, 0, 0);
        }

        // ---- 2-way K reduction: kh=1 writes b128 partials, kh=0 adds ----
        if (kh == 1) {
            char* bp = bufb + ((size_t)(s * 4) * 64 + l) * 16;
            *(f32x4*)(bp + 0 * 1024) = aR;
            *(f32x4*)(bp + 1 * 1024) = aZ;
            *(f32x4*)(bp + 2 * 1024) = aIN;
            *(f32x4*)(bp + 3 * 1024) = aHN;
        }
        __syncthreads();   // [C]

        if (kh == 0) {
            const char* bp = bufb + ((size_t)(s * 4) * 64 + l) * 16;
            aR  += *(const f32x4*)(bp + 0 * 1024);
            aZ  += *(const f32x4*)(bp + 1 * 1024);
            aIN += *(const f32x4*)(bp + 2 * 1024);
            aHN += *(const f32x4*)(bp + 3 * 1024);

            // ---- gates + state update; h(t+1) bf16 into LDS tile ----
            #pragma unroll
            for (int r = 0; r < 4; r++) {
                float pr = aR[r] + bR;
                float pz = aZ[r] + bZ;
                float rg = 1.f / (1.f + expf(-pr));
                float zg = 1.f / (1.f + expf(-pz));
                float ng = tanhf(aIN[r] + bIN + rg * (aHN[r] + bHN));
                float hn = (1.f - zg) * ng + zg * hreg[r];
                hreg[r] = hn;
                int lb = s * 16 + q * 4 + r;          // local batch 0..63
                htile[lb * 16 + ln] = f2bf(hn);
                if (t == T_STEPS - 1) hF[(size_t)(bb + lb) * HID + gu] = hn;
            }
        }
        __syncthreads();   // [E] htile complete

        // ---- packed coherent h store: thread i -> (batch i/4, unit-quad i%4) ----
        if (tid < 256) {
            int lb = tid >> 2;
            int ug = (tid & 3) * 4;
            unsigned long long pk = *(const unsigned long long*)(&htile[lb * 16 + ug]);
            __hip_atomic_store(hwr + ((((size_t)(bb + lb)) * HID + u0 + ug) >> 2), pk,
                               __ATOMIC_RELAXED, __HIP_MEMORY_SCOPE_AGENT);
        }

        __syncthreads();   // [D] vmcnt(0) drain: all h stores coherent-visible
        if (tid == 0)
            __hip_atomic_fetch_add(flags + (size_t)t * 4 + g, 1u,
                                   __ATOMIC_RELAXED, __HIP_MEMORY_SCOPE_AGENT);
    }
}

// out[b][o] = h[b] . W_out[o] + b_out[o]
__global__ void out_proj(const float* __restrict__ h, const float* __restrict__ Wout,
                         const float* __restrict__ bout, float* __restrict__ out) {
    int b = blockIdx.x;    // 256
    int o = threadIdx.x;   // 128
    const float* hr = h + (size_t)b * HID;
    const float* wr = Wout + (size_t)o * HID;
    float s0 = 0.f, s1 = 0.f, s2 = 0.f, s3 = 0.f;
    for (int u = 0; u < HID; u += 4) {
        s0 += hr[u + 0] * wr[u + 0];
        s1 += hr[u + 1] * wr[u + 1];
        s2 += hr[u + 2] * wr[u + 2];
        s3 += hr[u + 3] * wr[u + 3];
    }
    out[b * OUTD + o] = (s0 + s1) + (s2 + s3) + bout[o];
}

extern "C" void kernel_launch(void* const* d_in, const int* in_sizes, int n_in,
                              void* d_out, int out_size, void* d_ws, size_t ws_size,
                              hipStream_t stream) {
    const float* x     = (const float*)d_in[0];
    const float* mask  = (const float*)d_in[1];
    const float* ti    = (const float*)d_in[2];
    const float* W_ih  = (const float*)d_in[3];
    const float* W_hh  = (const float*)d_in[4];
    const float* b_ih  = (const float*)d_in[5];
    const float* b_hh  = (const float*)d_in[6];
    const float* W_out = (const float*)d_in[7];
    const float* b_out = (const float*)d_in[8];
    float* out = (float*)d_out;

    char* ws = (char*)d_ws;
    unsigned int* flags     = (unsigned int*)ws;                        // 8192 B
    unsigned long long* hb0 = (unsigned long long*)(ws + 8192);         // 512 KB
    unsigned long long* hb1 = (unsigned long long*)(ws + 8192 + 524288);
    float* hF               = (float*)(ws + 8192 + 2 * 524288);         // 1 MB
    unsigned short* xtb     = (unsigned short*)(ws + 8192 + 2 * 524288 + 1048576);

    // zero flags + h(0) (contiguous)
    (void)hipMemsetAsync(ws, 0, 8192 + 524288, stream);

    build_xt<<<4096, 256, 0, stream>>>(x, mask, ti, xtb);

    (void)hipFuncSetAttribute((const void*)gru_persist,
                              hipFuncAttributeMaxDynamicSharedMemorySize, LDS_BYTES);

    gru_persist<<<256, 512, LDS_BYTES, stream>>>(xtb, W_ih, W_hh, b_ih, b_hh,
                                                 hb0, hb1, hF, flags);

    out_proj<<<256, 128, 0, stream>>>(hF, W_out, b_out, out);
}